// Round 1
// baseline (765.736 us; speedup 1.0000x reference)
//
#include <hip/hip_runtime.h>

// Antialiased bilinear downsample (JAX triangle filter, scale=1/4 both axes):
//   in  (2048, 6, 128, 96) fp32
//   out (2048, 6, 32, 24) fp32  (reshape to (-1,6,768) is a no-op on flat layout)
//
// Separable 8-tap filter per axis. Interior weights [1,3,5,7,7,5,3,1]/32.
// Edge outputs (o==0 / o==last) lose 2 taps and renormalize by 3.5.
//
// v2 structure: vertical pass FIRST, directly from global (coalesced float4,
// re-reads of the 4-row window overlap are absorbed by L1/L2), tiny 12.8 KB
// LDS intermediate, ONE barrier, horizontal pass from LDS. This replaces the
// v1 structure (48 KB full-image LDS staging, 64 KB LDS total, 2 blocks/CU,
// 3 barrier-separated phases) which left the memory pipe idle during compute.

#define IMG_H 128
#define IMG_W 96
#define IN_W4 24      // float4s per input row
#define ROUT_H 32
#define ROUT_W 24
#define MSTRIDE 100   // intermediate row stride in floats (400B, 16B-aligned)

__global__ __launch_bounds__(256, 4)
void resize_aa_kernel(const float* __restrict__ x, float* __restrict__ out) {
    __shared__ float s_mid[ROUT_H * MSTRIDE];   // 12800 B

    const int img = blockIdx.x;
    const int tid = threadIdx.x;
    const float4* __restrict__ src4 =
        (const float4*)(x + (size_t)img * (IMG_H * IMG_W));

    // ---- Phase 1: vertical 128 -> 32, straight from global ----
    // 768 float4 outputs (32 oh x 24 col4), 3 per thread. Lanes within a
    // 24-lane group read consecutive float4 -> 384B contiguous segments.
    // Each input row is read by exactly 2 adjacent oh windows; those reads
    // are near-simultaneous within the block -> L1/L2 hits, HBM sees 48KB.
#pragma unroll
    for (int k = 0; k < 3; ++k) {
        const int idx = tid + k * 256;          // 0..767
        const int oh  = idx / IN_W4;
        const int c4  = idx - oh * IN_W4;
        const int r0  = 4 * oh - 2;

        float w0 = 1.f/32, w1 = 3.f/32, w2 = 5.f/32, w3 = 7.f/32,
              w4 = 7.f/32, w5 = 5.f/32, w6 = 3.f/32, w7 = 1.f/32;
        if (oh == 0) {
            const float s = 1.0f / 3.5f;
            w0 = 0.f;        w1 = 0.f;
            w2 = 0.625f * s; w3 = 0.875f * s; w4 = 0.875f * s;
            w5 = 0.625f * s; w6 = 0.375f * s; w7 = 0.125f * s;
        } else if (oh == ROUT_H - 1) {
            const float s = 1.0f / 3.5f;
            w0 = 0.125f * s; w1 = 0.375f * s; w2 = 0.625f * s;
            w3 = 0.875f * s; w4 = 0.875f * s; w5 = 0.625f * s;
            w6 = 0.f;        w7 = 0.f;
        }
        const float wt[8] = {w0, w1, w2, w3, w4, w5, w6, w7};

        float4 acc = make_float4(0.f, 0.f, 0.f, 0.f);
#pragma unroll
        for (int t = 0; t < 8; ++t) {
            int r = r0 + t;
            r = r < 0 ? 0 : (r > IMG_H - 1 ? IMG_H - 1 : r);  // clamp; w==0 on OOB taps
            float4 v = src4[r * IN_W4 + c4];
            acc.x += wt[t] * v.x; acc.y += wt[t] * v.y;
            acc.z += wt[t] * v.z; acc.w += wt[t] * v.w;
        }
        *(float4*)(&s_mid[oh * MSTRIDE + 4 * c4]) = acc;
    }
    __syncthreads();

    // ---- Phase 2: horizontal 96 -> 24 from LDS, coalesced stores ----
    float* __restrict__ dst = out + (size_t)img * (ROUT_H * ROUT_W);
#pragma unroll
    for (int k = 0; k < 3; ++k) {
        const int idx = tid + k * 256;          // 0..767
        const int oh  = idx / ROUT_W;
        const int ow  = idx - oh * ROUT_W;
        const float* rowp = &s_mid[oh * MSTRIDE];

        // taps: prev.z prev.w cur.x cur.y cur.z cur.w next.x next.y
        // Clamped indices feed garbage only into zero-weight taps (finite data).
        const int pi = (ow > 0)          ? ow - 1 : 0;
        const int ni = (ow < ROUT_W - 1) ? ow + 1 : ROUT_W - 1;
        const float4 prev = *(const float4*)(rowp + 4 * pi);
        const float4 cur  = *(const float4*)(rowp + 4 * ow);
        const float4 next = *(const float4*)(rowp + 4 * ni);

        float w0 = 1.f/32, w1 = 3.f/32, w2 = 5.f/32, w3 = 7.f/32,
              w4 = 7.f/32, w5 = 5.f/32, w6 = 3.f/32, w7 = 1.f/32;
        if (ow == 0) {
            const float s = 1.0f / 3.5f;
            w0 = 0.f;        w1 = 0.f;
            w2 = 0.625f * s; w3 = 0.875f * s; w4 = 0.875f * s;
            w5 = 0.625f * s; w6 = 0.375f * s; w7 = 0.125f * s;
        } else if (ow == ROUT_W - 1) {
            const float s = 1.0f / 3.5f;
            w0 = 0.125f * s; w1 = 0.375f * s; w2 = 0.625f * s;
            w3 = 0.875f * s; w4 = 0.875f * s; w5 = 0.625f * s;
            w6 = 0.f;        w7 = 0.f;
        }

        const float acc = w0 * prev.z + w1 * prev.w
                        + w2 * cur.x  + w3 * cur.y + w4 * cur.z + w5 * cur.w
                        + w6 * next.x + w7 * next.y;
        dst[idx] = acc;
    }
}

extern "C" void kernel_launch(void* const* d_in, const int* in_sizes, int n_in,
                              void* d_out, int out_size, void* d_ws, size_t ws_size,
                              hipStream_t stream) {
    const float* x = (const float*)d_in[0];   // (2048, 6, 128, 96) fp32
    // d_in[1] (y) is unused by the forward pass.
    float* out = (float*)d_out;               // (2048*6*768,) fp32
    const int n_img = 2048 * 6;
    resize_aa_kernel<<<n_img, 256, 0, stream>>>(x, out);
}